// Round 4
// baseline (106.767 us; speedup 1.0000x reference)
//
#include <hip/hip_runtime.h>
#include <hip/hip_cooperative_groups.h>

namespace cg = cooperative_groups;

#define N 512
#define D 384
#define NF4 (D / 4)   // 96 float4 per embedding row

#if __has_builtin(__builtin_amdgcn_exp2f)
#define EXP2F(x) __builtin_amdgcn_exp2f(x)
#else
#define EXP2F(x) exp2f(x)
#endif
#if __has_builtin(__builtin_amdgcn_rcpf)
#define RCPF(x) __builtin_amdgcn_rcpf(x)
#else
#define RCPF(x) (1.0f / (x))
#endif

// 16-lane-row reduction via DPP (VALU pipe). row_shr:N + bound_ctrl=0-fill;
// after shr 1,2,4,8 the 16-lane sum sits in lane 15 of each row.
__device__ __forceinline__ float row16_sum(float x) {
    int v;
    v = __builtin_amdgcn_update_dpp(0, __float_as_int(x), 0x111, 0xF, 0xF, true);
    x += __int_as_float(v);
    v = __builtin_amdgcn_update_dpp(0, __float_as_int(x), 0x112, 0xF, 0xF, true);
    x += __int_as_float(v);
    v = __builtin_amdgcn_update_dpp(0, __float_as_int(x), 0x114, 0xF, 0xF, true);
    x += __int_as_float(v);
    v = __builtin_amdgcn_update_dpp(0, __float_as_int(x), 0x118, 0xF, 0xF, true);
    x += __int_as_float(v);
    return x;
}

// Single cooperative kernel: dist + softrank-loss + final mean.
// One block per query pair {b, b+256}, 512 threads, 256 blocks (1/CU, all
// co-resident -> grid.sync() legal). Phases 1-2 are byte-identical to the
// round-3 verified code; the former final_kernel becomes a post-grid-sync
// reduce in block 0, removing one dispatch latency (~2 us) + launch gap.
__global__ __launch_bounds__(512) void fused_kernel(const float* __restrict__ emb,
                                                    const int* __restrict__ labels,
                                                    float* __restrict__ prec,
                                                    float* __restrict__ out) {
    const int b = blockIdx.x;          // q0 = b, q1 = b + 256
    const int t = threadIdx.x;         // 0..511 (8 waves)
    const int lane = t & 63, wave = t >> 6;
    const int g = lane >> 4, p = lane & 15;   // 16-lane group, pos in group
    const int q0 = b, q1 = b + 256;

    __shared__ float s0[N];            // C-scaled distance row of q0
    __shared__ float s1[N];            // C-scaled distance row of q1
    __shared__ short gt0[N], gt1[N];   // GT column indices
    __shared__ int n0, n1;
    __shared__ float wnum[8];

    if (t == 0) { n0 = 0; n1 = 0; }
    __syncthreads();                   // order n0/n1 init before atomics

    // GT lists (overlaps with phase-1 issue; the phase-1/2 barrier covers it).
    const int lt  = labels[t];
    const int lq0 = labels[q0], lq1 = labels[q1];
    if (lt == lq0 && t != q0) { int pi = atomicAdd(&n0, 1); gt0[pi] = (short)t; }
    if (lt == lq1 && t != q1) { int pi = atomicAdd(&n1, 1); gt1[pi] = (short)t; }

    // Query fragments -> registers (lane p only ever needs k4 = p+16i).
    const float4* embf4 = (const float4*)emb;
    float4 u0[6], u1[6];
#pragma unroll
    for (int i = 0; i < 6; ++i) {
        u0[i] = embf4[(size_t)q0 * NF4 + p + 16 * i];
        u1[i] = embf4[(size_t)q1 * NF4 + p + 16 * i];
    }

    const float C = 144.26950408889634f;  // (1/T2) * log2(e)
    const int rowId = (wave << 2) + g;    // 0..31: row offset within a pass

#pragma unroll 2
    for (int pass = 0; pass < 16; ++pass) {
        const int j = (pass << 5) + rowId;
        const float4* rp = embf4 + (size_t)j * NF4 + p;
        float a0 = 0.f, a1 = 0.f;
#pragma unroll
        for (int i = 0; i < 6; ++i) {
            float4 v = rp[16 * i];        // 16 lanes: 256 B contiguous
            float e;
            e = v.x - u0[i].x; a0 += e * e;  e = v.y - u0[i].y; a0 += e * e;
            e = v.z - u0[i].z; a0 += e * e;  e = v.w - u0[i].w; a0 += e * e;
            e = v.x - u1[i].x; a1 += e * e;  e = v.y - u1[i].y; a1 += e * e;
            e = v.z - u1[i].z; a1 += e * e;  e = v.w - u1[i].w; a1 += e * e;
        }
        a0 = row16_sum(a0);               // sum -> lane p==15 of each group
        a1 = row16_sum(a1);
        if (p == 15) {
            float d0 = sqrtf(fmaxf(a0, 1e-12f)) * C;
            float d1 = sqrtf(fmaxf(a1, 1e-12f)) * C;
            if (j == q0) d0 = 1e6f * C;   // self pair -> BIG
            if (j == q1) d1 = 1e6f * C;
            s0[j] = d0;
            s1[j] = d1;
        }
    }
    __syncthreads();

    // ---- Phase 2: soft-rank only for GT columns (~8 of 512 per query) ----
    const float* s  = (wave < 4) ? s0 : s1;
    const short* gt = (wave < 4) ? gt0 : gt1;
    const int    n  = (wave < 4) ? n0 : n1;
    const int    wq = wave & 3;
    float mynum = 0.f;
    for (int i = wq; i < n; i += 4) {
        const float sj = s[gt[i]];
        float r = 0.f;
#pragma unroll
        for (int m = lane; m < N; m += 64)       // 8 iters, stride-1 LDS
            r += RCPF(1.f + EXP2F(s[m] - sj));   // sigmoid((d_j - d_m)/T2)
#pragma unroll
        for (int off = 32; off > 0; off >>= 1) r += __shfl_down(r, off);
        if (lane == 0)
            mynum += RCPF(1.f + EXP2F((r - 5.f) * 1.4426950408889634f));
    }
    if (lane == 0) wnum[wave] = mynum;
    __syncthreads();
    if (t == 0) {
        float num0 = wnum[0] + wnum[1] + wnum[2] + wnum[3];
        prec[q0] = num0 / fminf((float)n0, 5.f);   // n==0 -> NaN, matches ref
    } else if (t == 64) {
        float num1 = wnum[4] + wnum[5] + wnum[6] + wnum[7];
        prec[q1] = num1 / fminf((float)n1, 5.f);
    }

    // ---- Final: 1 - mean(prec), block 0 after grid-wide sync ----
    cg::this_grid().sync();
    if (b == 0) {
        __shared__ float w[8];
        float v = prec[t];
#pragma unroll
        for (int off = 32; off > 0; off >>= 1) v += __shfl_down(v, off);
        if (lane == 0) w[wave] = v;
        __syncthreads();
        if (t == 0) {
            float tot = w[0] + w[1] + w[2] + w[3] + w[4] + w[5] + w[6] + w[7];
            out[0] = 1.0f - tot * (1.0f / 512.0f);
        }
    }
}

extern "C" void kernel_launch(void* const* d_in, const int* in_sizes, int n_in,
                              void* d_out, int out_size, void* d_ws, size_t ws_size,
                              hipStream_t stream) {
    const float* emb  = (const float*)d_in[0];
    const int* labels = (const int*)d_in[1];
    float* out        = (float*)d_out;
    float* prec       = (float*)d_ws;    // 512 floats (write-before-read)

    void* args[] = {(void*)&emb, (void*)&labels, (void*)&prec, (void*)&out};
    hipLaunchCooperativeKernel(reinterpret_cast<void*>(fused_kernel),
                               dim3(N / 2), dim3(512), args, 0, stream);
}

// Round 5
// 75.066 us; speedup vs baseline: 1.4223x; 1.4223x over previous
//
#include <hip/hip_runtime.h>

#define N 512
#define D 384
#define NF4 (D / 4)   // 96 float4 per embedding row

#if __has_builtin(__builtin_amdgcn_exp2f)
#define EXP2F(x) __builtin_amdgcn_exp2f(x)
#else
#define EXP2F(x) exp2f(x)
#endif
#if __has_builtin(__builtin_amdgcn_rcpf)
#define RCPF(x) __builtin_amdgcn_rcpf(x)
#else
#define RCPF(x) (1.0f / (x))
#endif

// 16-lane-row reduction via DPP (VALU pipe). row_shr:N + bound_ctrl=0-fill;
// after shr 1,2,4,8 the 16-lane sum sits in lane 15 of each row.
__device__ __forceinline__ float row16_sum(float x) {
    int v;
    v = __builtin_amdgcn_update_dpp(0, __float_as_int(x), 0x111, 0xF, 0xF, true);
    x += __int_as_float(v);
    v = __builtin_amdgcn_update_dpp(0, __float_as_int(x), 0x112, 0xF, 0xF, true);
    x += __int_as_float(v);
    v = __builtin_amdgcn_update_dpp(0, __float_as_int(x), 0x114, 0xF, 0xF, true);
    x += __int_as_float(v);
    v = __builtin_amdgcn_update_dpp(0, __float_as_int(x), 0x118, 0xF, 0xF, true);
    x += __int_as_float(v);
    return x;
}

// Single regular-dispatch fused kernel (round-3 verified math) + last-block
// finalize. ws[0] (float acc) and ws[1] (int ticket) are zeroed by an 8-byte
// hipMemsetAsync before launch. Each block atomicAdds its two per-query
// precisions (one add), __threadfence(), takes a ticket; ticket 255 knows
// every other block's acc-add is visible (add -> fence -> ticket ordering,
// device-scope atomics) and writes out = 1 - acc/512.
// NOTE: cooperative launch for this was +37 us of per-iteration launch
// overhead (round 4) -- regular dispatch + ticket is the cheap form.
__global__ __launch_bounds__(512) void fused_kernel(const float* __restrict__ emb,
                                                    const int* __restrict__ labels,
                                                    float* __restrict__ acc,
                                                    int* __restrict__ cnt,
                                                    float* __restrict__ out) {
    const int b = blockIdx.x;          // q0 = b, q1 = b + 256
    const int t = threadIdx.x;         // 0..511 (8 waves)
    const int lane = t & 63, wave = t >> 6;
    const int g = lane >> 4, p = lane & 15;   // 16-lane group, pos in group
    const int q0 = b, q1 = b + 256;

    __shared__ float s0[N];            // C-scaled distance row of q0
    __shared__ float s1[N];            // C-scaled distance row of q1
    __shared__ short gt0[N], gt1[N];   // GT column indices
    __shared__ int n0, n1;
    __shared__ float wnum[8];

    if (t == 0) { n0 = 0; n1 = 0; }
    __syncthreads();                   // order n0/n1 init before atomics

    // GT lists (overlaps with phase-1 issue; the phase-1/2 barrier covers it).
    const int lt  = labels[t];
    const int lq0 = labels[q0], lq1 = labels[q1];
    if (lt == lq0 && t != q0) { int pi = atomicAdd(&n0, 1); gt0[pi] = (short)t; }
    if (lt == lq1 && t != q1) { int pi = atomicAdd(&n1, 1); gt1[pi] = (short)t; }

    // Query fragments -> registers (lane p only ever needs k4 = p+16i).
    const float4* embf4 = (const float4*)emb;
    float4 u0[6], u1[6];
#pragma unroll
    for (int i = 0; i < 6; ++i) {
        u0[i] = embf4[(size_t)q0 * NF4 + p + 16 * i];
        u1[i] = embf4[(size_t)q1 * NF4 + p + 16 * i];
    }

    const float C = 144.26950408889634f;  // (1/T2) * log2(e)
    const int rowId = (wave << 2) + g;    // 0..31: row offset within a pass

#pragma unroll 2
    for (int pass = 0; pass < 16; ++pass) {
        const int j = (pass << 5) + rowId;
        const float4* rp = embf4 + (size_t)j * NF4 + p;
        float a0 = 0.f, a1 = 0.f;
#pragma unroll
        for (int i = 0; i < 6; ++i) {
            float4 v = rp[16 * i];        // 16 lanes: 256 B contiguous
            float e;
            e = v.x - u0[i].x; a0 += e * e;  e = v.y - u0[i].y; a0 += e * e;
            e = v.z - u0[i].z; a0 += e * e;  e = v.w - u0[i].w; a0 += e * e;
            e = v.x - u1[i].x; a1 += e * e;  e = v.y - u1[i].y; a1 += e * e;
            e = v.z - u1[i].z; a1 += e * e;  e = v.w - u1[i].w; a1 += e * e;
        }
        a0 = row16_sum(a0);               // sum -> lane p==15 of each group
        a1 = row16_sum(a1);
        if (p == 15) {
            float d0 = sqrtf(fmaxf(a0, 1e-12f)) * C;
            float d1 = sqrtf(fmaxf(a1, 1e-12f)) * C;
            if (j == q0) d0 = 1e6f * C;   // self pair -> BIG
            if (j == q1) d1 = 1e6f * C;
            s0[j] = d0;
            s1[j] = d1;
        }
    }
    __syncthreads();

    // ---- Phase 2: soft-rank only for GT columns (~8 of 512 per query) ----
    const float* s  = (wave < 4) ? s0 : s1;
    const short* gt = (wave < 4) ? gt0 : gt1;
    const int    n  = (wave < 4) ? n0 : n1;
    const int    wq = wave & 3;
    float mynum = 0.f;
    for (int i = wq; i < n; i += 4) {
        const float sj = s[gt[i]];
        float r = 0.f;
#pragma unroll
        for (int m = lane; m < N; m += 64)       // 8 iters, stride-1 LDS
            r += RCPF(1.f + EXP2F(s[m] - sj));   // sigmoid((d_j - d_m)/T2)
#pragma unroll
        for (int off = 32; off > 0; off >>= 1) r += __shfl_down(r, off);
        if (lane == 0)
            mynum += RCPF(1.f + EXP2F((r - 5.f) * 1.4426950408889634f));
    }
    if (lane == 0) wnum[wave] = mynum;
    __syncthreads();

    // ---- Block partial -> global accumulator; last ticket finalizes ----
    if (t == 0) {
        float num0 = wnum[0] + wnum[1] + wnum[2] + wnum[3];
        float num1 = wnum[4] + wnum[5] + wnum[6] + wnum[7];
        // n==0 -> 0/0 = NaN, propagates through the sum like the reference mean
        float part = num0 / fminf((float)n0, 5.f) + num1 / fminf((float)n1, 5.f);
        atomicAdd(acc, part);
        __threadfence();                       // acc-add visible before ticket
        int ticket = atomicAdd(cnt, 1);
        if (ticket == N / 2 - 1) {             // last block: all adds visible
            __threadfence();
            float tot = atomicAdd(acc, 0.0f);  // coherent atomic read
            out[0] = 1.0f - tot * (1.0f / 512.0f);
        }
    }
}

extern "C" void kernel_launch(void* const* d_in, const int* in_sizes, int n_in,
                              void* d_out, int out_size, void* d_ws, size_t ws_size,
                              hipStream_t stream) {
    const float* emb  = (const float*)d_in[0];
    const int* labels = (const int*)d_in[1];
    float* out        = (float*)d_out;
    float* acc        = (float*)d_ws;          // ws[0] = sum accumulator
    int*   cnt        = (int*)d_ws + 1;        // ws[1] = ticket counter

    hipMemsetAsync(d_ws, 0, 8, stream);        // graph-capture-safe tiny fill
    hipLaunchKernelGGL(fused_kernel, dim3(N / 2), dim3(512), 0, stream,
                       emb, labels, acc, cnt, out);
}